// Round 1
// baseline (122.563 us; speedup 1.0000x reference)
//
#include <hip/hip_runtime.h>

// RASP pairwise score, N=6144 atoms, P = N(N-1)/2 pairs.
// pot tensor [K=6, T=85, T=85, D=21] fp32 = 3.64 MB (fits in per-XCD L2).
// Strategy: counting-sort atoms by type (gather locality), then 128x128
// pair tiles; per-pair: distance, 2 gathers, lerp, masked sum.

#define T_TYPES 85
#define D_BINS 21
#define TSTRIDE (T_TYPES * D_BINS)            // 1785
#define KSTRIDE (T_TYPES * T_TYPES * D_BINS)  // 151725
#define INVALID_KEY 85
#define TILE 128

__global__ void hist_kernel(const int* __restrict__ types, int n, int* __restrict__ hist) {
    int i = blockIdx.x * blockDim.x + threadIdx.x;
    if (i < n) {
        int t = types[i];
        int key = (t < 0) ? INVALID_KEY : t;
        atomicAdd(&hist[key], 1);
    }
}

__global__ void scan_kernel(const int* __restrict__ hist, int* __restrict__ offs) {
    if (threadIdx.x == 0 && blockIdx.x == 0) {
        int s = 0;
        for (int i = 0; i < INVALID_KEY + 1; ++i) { offs[i] = s; s += hist[i]; }
    }
}

__global__ void scatter_kernel(const float* __restrict__ coords,
                               const int* __restrict__ res_ids,
                               const int* __restrict__ types, int n,
                               int* __restrict__ offs, float4* __restrict__ sorted) {
    int i = blockIdx.x * blockDim.x + threadIdx.x;
    if (i < n) {
        int t = types[i];
        int key = (t < 0) ? INVALID_KEY : t;
        int pos = atomicAdd(&offs[key], 1);
        float4 v;
        v.x = coords[3 * i + 0];
        v.y = coords[3 * i + 1];
        v.z = coords[3 * i + 2];
        v.w = __int_as_float((res_ids[i] << 7) | key);
        sorted[pos] = v;
    }
}

__global__ __launch_bounds__(TILE) void pair_kernel(const float4* __restrict__ sorted,
                                                    const float* __restrict__ pot,
                                                    int n, int nt,
                                                    float* __restrict__ out) {
    __shared__ float4 jtile[TILE];
    __shared__ float wsum[TILE / 64];

    int b = blockIdx.x;
    // decode triangular (bi, bj), bi <= bj; row_start(r) = r*nt - r*(r-1)/2
    int bi = (int)((2.0 * nt + 1.0 -
                    sqrt((2.0 * nt + 1.0) * (2.0 * nt + 1.0) - 8.0 * (double)b)) * 0.5);
    if (bi < 0) bi = 0;
    if (bi > nt - 1) bi = nt - 1;
    while ((bi + 1) * nt - ((bi + 1) * bi) / 2 <= b) ++bi;
    while (bi * nt - (bi * (bi - 1)) / 2 > b) --bi;
    int bj = bi + (b - (bi * nt - (bi * (bi - 1)) / 2));

    int tid = threadIdx.x;
    int q0 = bj * TILE;
    {
        int q = q0 + tid;
        float4 v;
        if (q < n) v = sorted[q];
        else { v.x = 0.f; v.y = 0.f; v.z = 0.f; v.w = __int_as_float(INVALID_KEY); }
        jtile[tid] = v;
    }
    __syncthreads();

    int p = bi * TILE + tid;
    float4 mine;
    if (p < n) mine = sorted[p];
    else { mine.x = 0.f; mine.y = 0.f; mine.z = 0.f; mine.w = __int_as_float(INVALID_KEY); }

    int packi = __float_as_int(mine.w);
    int keyi = packi & 127;
    int resi = packi >> 7;
    int vi = (keyi < INVALID_KEY) ? 1 : 0;
    int tbase = keyi * TSTRIDE;

    float acc = 0.0f;
#pragma unroll 4
    for (int jj = 0; jj < TILE; ++jj) {
        float4 o = jtile[jj];
        int q = q0 + jj;
        float dx = mine.x - o.x;
        float dy = mine.y - o.y;
        float dz = mine.z - o.z;
        float d2 = dx * dx + dy * dy + dz * dz;
        float dist = __builtin_amdgcn_sqrtf(d2) + 1e-8f;

        int packj = __float_as_int(o.w);
        int keyj = packj & 127;
        int resj = packj >> 7;
        int sep = resi - resj;
        sep = (sep < 0) ? -sep : sep;

        int valid = (q > p) & vi & (keyj < INVALID_KEY) & (sep > 2) & (dist < 20.0f);

        int k = sep - 1;
        k = (k < 0) ? 0 : k;
        k = (k > 5) ? 5 : k;

        int d0 = (int)dist;
        d0 = (d0 > 19) ? 19 : d0;
        float alpha = dist - (float)d0;

        int idx = k * KSTRIDE + tbase + keyj * D_BINS + d0;
        idx = valid ? idx : 0;
        float e0 = pot[idx];
        float e1 = pot[idx + 1];
        float val = __builtin_fmaf(alpha, e1 - e0, e0) - 2.7f;
        acc += valid ? val : 0.0f;
    }

    // wave (64-lane) reduce then block reduce then one atomic
#pragma unroll
    for (int off = 32; off > 0; off >>= 1)
        acc += __shfl_down(acc, off, 64);
    int wave = tid >> 6;
    int lane = tid & 63;
    if (lane == 0) wsum[wave] = acc;
    __syncthreads();
    if (tid == 0) {
        float s = 0.f;
        for (int w = 0; w < TILE / 64; ++w) s += wsum[w];
        atomicAdd(out, s);
    }
}

extern "C" void kernel_launch(void* const* d_in, const int* in_sizes, int n_in,
                              void* d_out, int out_size, void* d_ws, size_t ws_size,
                              hipStream_t stream) {
    const float* coords = (const float*)d_in[0];
    const int* res_ids = (const int*)d_in[1];
    const int* types   = (const int*)d_in[2];
    const float* pot   = (const float*)d_in[3];
    int n = in_sizes[1];
    float* out = (float*)d_out;

    int* hist = (int*)d_ws;          // 128 ints
    int* offs = hist + 128;          // 128 ints
    float4* sorted = (float4*)((char*)d_ws + 1024);

    hipMemsetAsync(d_ws, 0, 1024, stream);
    hipMemsetAsync(d_out, 0, sizeof(float), stream);

    int nb = (n + 255) / 256;
    hist_kernel<<<nb, 256, 0, stream>>>(types, n, hist);
    scan_kernel<<<1, 64, 0, stream>>>(hist, offs);
    scatter_kernel<<<nb, 256, 0, stream>>>(coords, res_ids, types, n, offs, sorted);

    int nt = (n + TILE - 1) / TILE;
    int nblocks = nt * (nt + 1) / 2;
    pair_kernel<<<nblocks, TILE, 0, stream>>>(sorted, pot, n, nt, out);
}

// Round 2
// 91.730 us; speedup vs baseline: 1.3361x; 1.3361x over previous
//
#include <hip/hip_runtime.h>

// RASP pairwise score, N=6144 atoms, P = N(N-1)/2 pairs.
// pot tensor [K=6, T=85, T=85, D=21] fp32 = 3.64 MB (fits in per-XCD L2).
// R2: fused single-block counting sort (1 dispatch instead of 3+2 memsets);
// pair kernel at 512 thr/block (8 waves) for latency hiding: thread =
// (i-lane, j-chunk-of-32) over a 128x128 tile.

#define T_TYPES 85
#define D_BINS 21
#define TSTRIDE (T_TYPES * D_BINS)            // 1785
#define KSTRIDE (T_TYPES * T_TYPES * D_BINS)  // 151725
#define INVALID_KEY 85
#define NKEYS 86
#define TILE 128
#define PAIR_THREADS 512
#define JCHUNK 32   // TILE / (PAIR_THREADS/TILE)

// One block does the whole counting sort (n=6144) + zeroes the output scalar.
__global__ __launch_bounds__(1024) void sort_kernel(const float* __restrict__ coords,
                                                    const int* __restrict__ res_ids,
                                                    const int* __restrict__ types, int n,
                                                    float4* __restrict__ sorted,
                                                    float* __restrict__ out) {
    __shared__ int hist[NKEYS];
    __shared__ int offs[NKEYS];
    int tid = threadIdx.x;
    if (tid < NKEYS) hist[tid] = 0;
    if (tid == 0) *out = 0.0f;
    __syncthreads();
    for (int i = tid; i < n; i += 1024) {
        int t = types[i];
        int key = (t < 0) ? INVALID_KEY : t;
        atomicAdd(&hist[key], 1);
    }
    __syncthreads();
    if (tid == 0) {
        int s = 0;
        for (int i = 0; i < NKEYS; ++i) { offs[i] = s; s += hist[i]; }
    }
    __syncthreads();
    for (int i = tid; i < n; i += 1024) {
        int t = types[i];
        int key = (t < 0) ? INVALID_KEY : t;
        int pos = atomicAdd(&offs[key], 1);
        float4 v;
        v.x = coords[3 * i + 0];
        v.y = coords[3 * i + 1];
        v.z = coords[3 * i + 2];
        v.w = __int_as_float((res_ids[i] << 7) | key);
        sorted[pos] = v;
    }
}

__global__ __launch_bounds__(PAIR_THREADS) void pair_kernel(const float4* __restrict__ sorted,
                                                            const float* __restrict__ pot,
                                                            int n, int nt,
                                                            float* __restrict__ out) {
    __shared__ float4 jtile[TILE];
    __shared__ float wsum[PAIR_THREADS / 64];

    int b = blockIdx.x;
    // decode triangular (bi, bj), bi <= bj; row_start(r) = r*nt - r*(r-1)/2
    int bi = (int)((2.0 * nt + 1.0 -
                    sqrt((2.0 * nt + 1.0) * (2.0 * nt + 1.0) - 8.0 * (double)b)) * 0.5);
    if (bi < 0) bi = 0;
    if (bi > nt - 1) bi = nt - 1;
    while ((bi + 1) * nt - ((bi + 1) * bi) / 2 <= b) ++bi;
    while (bi * nt - (bi * (bi - 1)) / 2 > b) --bi;
    int bj = bi + (b - (bi * nt - (bi * (bi - 1)) / 2));

    int tid = threadIdx.x;
    int ilane = tid & (TILE - 1);   // 0..127: which i in the tile
    int chunk = tid >> 7;           // 0..3: which 32-wide slice of j
    int q0 = bj * TILE;

    if (tid < TILE) {
        int q = q0 + tid;
        float4 v;
        if (q < n) v = sorted[q];
        else { v.x = 0.f; v.y = 0.f; v.z = 0.f; v.w = __int_as_float(INVALID_KEY); }
        jtile[tid] = v;
    }
    __syncthreads();

    int p = bi * TILE + ilane;
    float4 mine;
    if (p < n) mine = sorted[p];
    else { mine.x = 0.f; mine.y = 0.f; mine.z = 0.f; mine.w = __int_as_float(INVALID_KEY); }

    int packi = __float_as_int(mine.w);
    int keyi = packi & 127;
    int resi = packi >> 7;
    int vi = (keyi < INVALID_KEY) ? 1 : 0;
    int tbase = keyi * TSTRIDE;

    float acc = 0.0f;
    int j0 = chunk * JCHUNK;
#pragma unroll 8
    for (int u = 0; u < JCHUNK; ++u) {
        int jj = j0 + u;
        float4 o = jtile[jj];
        int q = q0 + jj;
        float dx = mine.x - o.x;
        float dy = mine.y - o.y;
        float dz = mine.z - o.z;
        float d2 = dx * dx + dy * dy + dz * dz;
        float dist = __builtin_amdgcn_sqrtf(d2) + 1e-8f;

        int packj = __float_as_int(o.w);
        int keyj = packj & 127;
        int resj = packj >> 7;
        int sep = resi - resj;
        sep = (sep < 0) ? -sep : sep;

        int valid = (q > p) & vi & (keyj < INVALID_KEY) & (sep > 2) & (dist < 20.0f);

        int k = sep - 1;
        k = (k < 0) ? 0 : k;
        k = (k > 5) ? 5 : k;

        int d0 = (int)dist;
        d0 = (d0 > 19) ? 19 : d0;
        float alpha = dist - (float)d0;

        int idx = k * KSTRIDE + tbase + keyj * D_BINS + d0;
        idx = valid ? idx : 0;
        float e0 = pot[idx];
        float e1 = pot[idx + 1];
        float val = __builtin_fmaf(alpha, e1 - e0, e0) - 2.7f;
        acc += valid ? val : 0.0f;
    }

    // wave (64-lane) reduce then block reduce then one atomic
#pragma unroll
    for (int off = 32; off > 0; off >>= 1)
        acc += __shfl_down(acc, off, 64);
    int wave = tid >> 6;
    int lane = tid & 63;
    if (lane == 0) wsum[wave] = acc;
    __syncthreads();
    if (tid == 0) {
        float s = 0.f;
#pragma unroll
        for (int w = 0; w < PAIR_THREADS / 64; ++w) s += wsum[w];
        atomicAdd(out, s);
    }
}

extern "C" void kernel_launch(void* const* d_in, const int* in_sizes, int n_in,
                              void* d_out, int out_size, void* d_ws, size_t ws_size,
                              hipStream_t stream) {
    const float* coords = (const float*)d_in[0];
    const int* res_ids = (const int*)d_in[1];
    const int* types   = (const int*)d_in[2];
    const float* pot   = (const float*)d_in[3];
    int n = in_sizes[1];
    float* out = (float*)d_out;

    float4* sorted = (float4*)d_ws;

    sort_kernel<<<1, 1024, 0, stream>>>(coords, res_ids, types, n, sorted, out);

    int nt = (n + TILE - 1) / TILE;
    int nblocks = nt * (nt + 1) / 2;
    pair_kernel<<<nblocks, PAIR_THREADS, 0, stream>>>(sorted, pot, n, nt, out);
}